// Round 7
// baseline (665.066 us; speedup 1.0000x reference)
//
#include <hip/hip_runtime.h>

#define DIM 512
#define N_ROWS 16384
#define K_CODES 8192
#define BK 32
#define TM 128
#define TN 128
#define NG (K_CODES / TN)               // 64 code groups
#define OUT_ELEMS (N_ROWS * DIM)        // 8388608
#define MARGIN 0.125f
#define RESCAN_CHUNK 1024
#define RESCAN_NCHUNK (K_CODES / RESCAN_CHUNK)  // 8
#define RESCAN_ROWS 16
#define NT (DIM / BK)                   // 16 K-steps

typedef _Float16 f16;
typedef _Float16 f16x8 __attribute__((ext_vector_type(8)));
typedef float f32x4 __attribute__((ext_vector_type(4)));

// monotone float->uint map: min on packed == (min dist, then min idx)
__device__ __forceinline__ unsigned long long pack_di(float d, int i) {
  unsigned u = __float_as_uint(d);
  u = (u & 0x80000000u) ? ~u : (u | 0x80000000u);
  return ((unsigned long long)u << 32) | (unsigned)i;
}

// ---------------- kernel 0: fp32 -> fp16 cast (x) ----------------
__global__ __launch_bounds__(256) void vq_split_kernel(const float* __restrict__ src,
                                                       f16* __restrict__ x16) {
  int i = (blockIdx.x * 256 + threadIdx.x) * 8;
  float4 v0 = *(const float4*)(src + i);
  float4 v1 = *(const float4*)(src + i + 4);
  float f[8] = {v0.x, v0.y, v0.z, v0.w, v1.x, v1.y, v1.z, v1.w};
  f16x8 h;
  #pragma unroll
  for (int j = 0; j < 8; ++j) h[j] = (f16)f[j];   // RNE, rel err <= 2^-11
  *(f16x8*)(x16 + i) = h;
}

// ---------------- kernel 1: emb fp16 cast + exact fp32 norms + counter zero ----------------
// one wave per code row: 64 lanes x 8 elems = 512
__global__ __launch_bounds__(256) void vq_split_enorm_kernel(
    const float* __restrict__ emb, f16* __restrict__ e16,
    float* __restrict__ enorm, int* __restrict__ counter) {
  int gid  = blockIdx.x * 256 + threadIdx.x;
  if (gid == 0) *counter = 0;
  int code = gid >> 6;
  int lane = gid & 63;
  size_t off = (size_t)code * DIM + lane * 8;
  float4 v0 = *(const float4*)(emb + off);
  float4 v1 = *(const float4*)(emb + off + 4);
  float f[8] = {v0.x, v0.y, v0.z, v0.w, v1.x, v1.y, v1.z, v1.w};
  f16x8 h;
  float s = 0.0f;
  #pragma unroll
  for (int j = 0; j < 8; ++j) {
    h[j] = (f16)f[j];
    s = fmaf(f[j], f[j], s);
  }
  *(f16x8*)(e16 + off) = h;
  #pragma unroll
  for (int o = 32; o > 0; o >>= 1) s += __shfl_down(s, o);
  if (lane == 0) enorm[code] = s;
}

// ---------------- async global->LDS 16B helper ----------------
__device__ __forceinline__ void gl2lds16(const f16* g, f16* l) {
  __builtin_amdgcn_global_load_lds((const __attribute__((address_space(1))) unsigned int*)g,
                                   (__attribute__((address_space(3))) unsigned int*)l,
                                   16, 0, 0);
}

__device__ __forceinline__ void top2_merge(float& d1, int& i1, float& d2,
                                           float od1, int oi1, float od2) {
  if (od1 < d1 || (od1 == d1 && oi1 < i1)) {
    d2 = fminf(d1, od2);
    d1 = od1; i1 = oi1;
  } else {
    d2 = fminf(d2, od1);
  }
}

// ---------------- kernel 2: single-term fp16 MFMA GEMM + top-2 argmin ----------------
// sim = x16.e16 (fp16 in, exact fp32 accumulate); dist = ||e||^2 - 2 sim.
// Rows with top-2 gap < MARGIN get the exact fp32 rescan, so argmin is exact.
//
// Structure: round-3-proven BK=32 double-buffer with stage-ahead, one
// __syncthreads per K-step (233 us). NEW this round: XCD-aware 2D chunk
// swizzle. Round-3 FETCH_SIZE was 143 MB vs 24 MB unique input -> ~6x L3/HBM
// re-fetch; bm-fastest dispatch gave co-resident blocks on an XCD disjoint
// operands, and L3-latency (~500cy) loads exceeded the 1-step stage-ahead
// cover. Swizzle gives each XCD 8bm x 16bn chunks: 1 MB x16 + 2 MB e16 = 3 MB
// working set < 4 MB per-XCD L2, so staging loads become L2 hits the existing
// stage-ahead CAN cover. Pure index remap; bijective by construction.
//
// LDS tiles [128][BK=32] f16; XOR swizzle (r0-proven, conflict-free): chunk fq
// of row r at slot fq ^ ((r>>1)&3); gl2lds writes linearly so the swizzle is
// realized source-side: lane l fetches chunk (l&3)^((l>>3)&3) of row l>>2.
__global__ __launch_bounds__(256, 4) void vq_argmin_mfma_kernel(
    const f16* __restrict__ x16, const f16* __restrict__ e16,
    const float* __restrict__ enorm,
    float* __restrict__ cand_d1, int* __restrict__ cand_i1, float* __restrict__ cand_d2) {
  __shared__ __align__(16) f16 Ax[2][TM * BK];   // 8 KB per buffer
  __shared__ __align__(16) f16 Be[2][TN * BK];   // 8 KB per buffer
  __shared__ float red_d1[2][TM];
  __shared__ int   red_i1[2][TM];
  __shared__ float red_d2[2][TM];

  const int tid  = threadIdx.x;
  const int wave = tid >> 6;
  const int lane = tid & 63;

  // ---- XCD-aware 2D chunk swizzle (bijective) ----
  // hw dispatch order: lin = bx + 128*by; XCD = lin & 7 (round-robin, m09).
  // Per-XCD sequence k walks 128-block chunks of 8bm x 16bn.
  const int lin    = blockIdx.x + 128 * blockIdx.y;
  const int xcd    = lin & 7;
  const int k      = lin >> 3;            // 0..1023 per xcd
  const int chunk  = k >> 7;              // 0..7
  const int within = k & 127;
  const int gchunk = chunk * 8 + xcd;     // 0..63, disjoint across xcds
  const int bm = (gchunk & 15) * 8  + (within >> 4);   // [0,128)
  const int bn = (gchunk >> 4) * 16 + (within & 15);   // [0,64)

  const int wr = (wave >> 1) * 64;   // wave's row offset in tile (compute role)
  const int wc = (wave & 1) * 64;    // wave's col offset in tile

  // staging role: waves 0,1 -> Ax halves; waves 2,3 -> Be halves.
  // 4 issues/wave/step, each issue = 16 rows x 4 swizzled 16B chunks.
  const f16* gsrc0;
  int ldoff;   // element offset of this wave's half within a tile buffer
  {
    const int srow = lane >> 2;                              // 0..15
    const int scg  = ((lane & 3) ^ ((lane >> 3) & 3)) * 8;   // swizzled chunk * 8 elems
    const int rowoff = (wave & 1) * 64;
    if (wave < 2) { gsrc0 = x16 + (size_t)(bm * TM + rowoff + srow) * DIM + scg; }
    else          { gsrc0 = e16 + (size_t)(bn * TN + rowoff + srow) * DIM + scg; }
    ldoff = rowoff * BK;
  }
  f16* dstA0 = (wave < 2) ? &Ax[0][ldoff] : &Be[0][ldoff];
  f16* dstA1 = (wave < 2) ? &Ax[1][ldoff] : &Be[1][ldoff];

  f32x4 acc[4][4];
  #pragma unroll
  for (int i = 0; i < 4; ++i)
    #pragma unroll
    for (int j = 0; j < 4; ++j)
      acc[i][j] = (f32x4){0.f, 0.f, 0.f, 0.f};

  const int fr = lane & 15;   // fragment row/col within 16
  const int fq = lane >> 4;   // k-quad
  const int sw8 = (fq ^ ((fr >> 1) & 3)) * 8;   // read-side swizzled chunk * 8 elems

  // prologue: stage K-step 0 into buffer 0
  #pragma unroll
  for (int i = 0; i < 4; ++i)
    gl2lds16(gsrc0 + (size_t)(16 * i) * DIM, dstA0 + (16 * i) * BK);
  __syncthreads();   // vmcnt(0) drain: step-0 tiles resident

  #pragma unroll 2
  for (int s = 0; s < NT; ++s) {
    const int cur = s & 1;
    // stage-ahead: next K-step into the other buffer BEFORE compute.
    // Safe: buf^1's readers finished before the barrier ending step s-1.
    if (s + 1 < NT) {
      f16* nb = cur ? dstA0 : dstA1;
      const int k1 = (s + 1) * BK;
      #pragma unroll
      for (int i = 0; i < 4; ++i)
        gl2lds16(gsrc0 + (size_t)(16 * i) * DIM + k1, nb + (16 * i) * BK);
    }

    const f16* A = cur ? &Ax[1][0] : &Ax[0][0];
    const f16* B = cur ? &Be[1][0] : &Be[0][0];
    f16x8 a[4], b[4];
    #pragma unroll
    for (int f = 0; f < 4; ++f) {
      a[f] = *(const f16x8*)&A[(wr + f * 16 + fr) * BK + sw8];
      b[f] = *(const f16x8*)&B[(wc + f * 16 + fr) * BK + sw8];
    }
    #pragma unroll
    for (int mf = 0; mf < 4; ++mf)
      #pragma unroll
      for (int nf = 0; nf < 4; ++nf)
        acc[mf][nf] = __builtin_amdgcn_mfma_f32_16x16x32_f16(a[mf], b[nf], acc[mf][nf], 0, 0, 0);

    __syncthreads();   // drains stage-ahead loads (covered by compute) + joins waves
  }

  // ---- epilogue: distances + per-row top-2 over this block's 128 cols ----
  float en[4];
  #pragma unroll
  for (int nf = 0; nf < 4; ++nf)
    en[nf] = enorm[bn * TN + wc + nf * 16 + fr];

  #pragma unroll
  for (int mf = 0; mf < 4; ++mf) {
    #pragma unroll
    for (int reg = 0; reg < 4; ++reg) {
      float d1 = 3.4e38f, d2 = 3.4e38f;
      int i1 = 0;
      #pragma unroll
      for (int nf = 0; nf < 4; ++nf) {   // ascending col keeps lowest idx on ties
        float d = en[nf] - 2.0f * acc[mf][nf][reg];
        int ci = bn * TN + wc + nf * 16 + fr;
        if (d < d1) { d2 = d1; d1 = d; i1 = ci; }
        else if (d < d2) { d2 = d; }
      }
      // butterfly over the 16 lanes (same fq) holding this row's 64 cols
      #pragma unroll
      for (int m = 1; m <= 8; m <<= 1) {
        float od1 = __shfl_xor(d1, m, 16);
        int   oi1 = __shfl_xor(i1, m, 16);
        float od2 = __shfl_xor(d2, m, 16);
        top2_merge(d1, i1, d2, od1, oi1, od2);
      }
      if (fr == 0) {
        int row = wr + mf * 16 + fq * 4 + reg;
        red_d1[wave & 1][row] = d1;
        red_i1[wave & 1][row] = i1;
        red_d2[wave & 1][row] = d2;
      }
    }
  }
  __syncthreads();
  if (tid < TM) {
    float d1 = red_d1[0][tid]; int i1 = red_i1[0][tid]; float d2 = red_d2[0][tid];
    top2_merge(d1, i1, d2, red_d1[1][tid], red_i1[1][tid], red_d2[1][tid]);
    size_t o = (size_t)bn * N_ROWS + (size_t)bm * TM + tid;
    cand_d1[o] = d1; cand_i1[o] = i1; cand_d2[o] = d2;
  }
}

// ---------------- kernel 3: merge 64 groups -> idx, flag + compacted work list ----------------
__global__ __launch_bounds__(256) void vq_merge2_kernel(
    const float* __restrict__ cd1, const int* __restrict__ ci1, const float* __restrict__ cd2,
    int* __restrict__ idx, int* __restrict__ flag,
    int* __restrict__ counter, int* __restrict__ flagged,
    unsigned long long* __restrict__ packed,
    float* __restrict__ loss_slot) {
  int r = blockIdx.x * 256 + threadIdx.x;
  if (r == 0) *loss_slot = 0.0f;
  float d1 = 3.4e38f, d2 = 3.4e38f;
  int i1 = 0;
  for (int g = 0; g < NG; ++g) {   // ascending g = ascending col blocks
    size_t o = (size_t)g * N_ROWS + r;
    top2_merge(d1, i1, d2, cd1[o], ci1[o], cd2[o]);
  }
  idx[r] = i1;
  int f = (d2 - d1 < MARGIN) ? 1 : 0;
  flag[r] = f;
  if (f) {
    packed[r] = 0xFFFFFFFFFFFFFFFFULL;
    int slot = atomicAdd(counter, 1);
    flagged[slot] = r;
  }
}

// ---------------- kernel 4: exact fp32 rescan, 16 rows per codebook pass ----------------
// Per-code arithmetic (s0..s3 lanes, (s0+s1)+(s2+s3)) kept bit-identical to the
// verified round-0 rescan; only the batching over rows changed (16 rows halves
// the codebook traffic vs 8).
__global__ __launch_bounds__(256) void vq_rescan_kernel(
    const float* __restrict__ x, const float* __restrict__ emb,
    const float* __restrict__ enorm,
    const int* __restrict__ counter, const int* __restrict__ flagged,
    unsigned long long* __restrict__ packed) {
  __shared__ float4 xs[RESCAN_ROWS][DIM / 4];          // 32 KB
  __shared__ unsigned long long wmin[4][RESCAN_ROWS];  // 512 B
  const int t  = threadIdx.x;
  const int wv = t >> 6, ln = t & 63;
  const int nflag   = counter[0];
  const int ngroups = (nflag + RESCAN_ROWS - 1) / RESCAN_ROWS;
  const int nitems  = ngroups * RESCAN_NCHUNK;
  for (int item = blockIdx.x; item < nitems; item += gridDim.x) {
    const int g  = item / RESCAN_NCHUNK;
    const int c0 = (item % RESCAN_NCHUNK) * RESCAN_CHUNK;
    __syncthreads();   // protect xs from previous iteration's readers
    #pragma unroll
    for (int u = 0; u < (RESCAN_ROWS * DIM / 4) / 256; ++u) {   // 8 iters
      int i4 = u * 256 + t;                 // 0..2047 float4 slots
      int j = i4 >> 7, kk = i4 & 127;
      int rj = g * RESCAN_ROWS + j;
      if (rj < nflag) xs[j][kk] = ((const float4*)(x + (size_t)flagged[rj] * DIM))[kk];
    }
    __syncthreads();
    unsigned long long best[RESCAN_ROWS];
    #pragma unroll
    for (int j = 0; j < RESCAN_ROWS; ++j) best[j] = ~0ULL;
    #pragma unroll
    for (int cc = 0; cc < RESCAN_CHUNK / 256; ++cc) {
      const int c = c0 + cc * 256 + t;
      const float4* e4 = (const float4*)(emb + (size_t)c * DIM);
      float s0[RESCAN_ROWS], s1[RESCAN_ROWS], s2[RESCAN_ROWS], s3[RESCAN_ROWS];
      #pragma unroll
      for (int j = 0; j < RESCAN_ROWS; ++j) { s0[j] = s1[j] = s2[j] = s3[j] = 0.f; }
      for (int k = 0; k < DIM / 4; ++k) {
        float4 ev = e4[k];
        #pragma unroll
        for (int j = 0; j < RESCAN_ROWS; ++j) {
          float4 xv = xs[j][k];              // broadcast read, conflict-free
          s0[j] = fmaf(xv.x, ev.x, s0[j]);
          s1[j] = fmaf(xv.y, ev.y, s1[j]);
          s2[j] = fmaf(xv.z, ev.z, s2[j]);
          s3[j] = fmaf(xv.w, ev.w, s3[j]);
        }
      }
      const float en = enorm[c];
      #pragma unroll
      for (int j = 0; j < RESCAN_ROWS; ++j) {
        float d = en - 2.0f * ((s0[j] + s1[j]) + (s2[j] + s3[j]));
        unsigned long long p = pack_di(d, c);
        if (p < best[j]) best[j] = p;
      }
    }
    // wave reduce (packed u64 min == lexicographic (dist, idx) min)
    #pragma unroll
    for (int j = 0; j < RESCAN_ROWS; ++j) {
      #pragma unroll
      for (int off = 32; off > 0; off >>= 1) {
        unsigned long long o = __shfl_down(best[j], off);
        if (o < best[j]) best[j] = o;
      }
    }
    if (ln == 0) {
      #pragma unroll
      for (int j = 0; j < RESCAN_ROWS; ++j) wmin[wv][j] = best[j];
    }
    __syncthreads();
    if (t < RESCAN_ROWS) {
      int rj = g * RESCAN_ROWS + t;
      if (rj < nflag) {
        unsigned long long m = wmin[0][t];
        if (wmin[1][t] < m) m = wmin[1][t];
        if (wmin[2][t] < m) m = wmin[2][t];
        if (wmin[3][t] < m) m = wmin[3][t];
        atomicMin(&packed[flagged[rj]], m);
      }
    }
  }
}

// ---------------- kernel 5: gather + outputs + loss ----------------
__global__ __launch_bounds__(256) void vq_gather_kernel(
    const float* __restrict__ x, const float* __restrict__ emb,
    const int* __restrict__ idx, const int* __restrict__ flag,
    const unsigned long long* __restrict__ packed,
    float* __restrict__ out, float* __restrict__ quant,
    float* __restrict__ loss_slot) {
  __shared__ float wsum[4];
  const int wave = threadIdx.x >> 6;
  const int lane = threadIdx.x & 63;
  const int row  = blockIdx.x * 4 + wave;
  const int code = flag[row] ? (int)(packed[row] & 0xFFFFFFFFu) : idx[row];
  const float4* xp = (const float4*)(x   + (size_t)row  * DIM + lane * 8);
  const float4* ep = (const float4*)(emb + (size_t)code * DIM + lane * 8);
  float s = 0.0f;
  #pragma unroll
  for (int t = 0; t < 2; ++t) {
    float4 xv = xp[t];
    float4 ev = ep[t];
    float dx = ev.x - xv.x, dy = ev.y - xv.y, dz = ev.z - xv.z, dw = ev.w - xv.w;
    s += dx * dx + dy * dy + dz * dz + dw * dw;
    ((float4*)(out   + (size_t)row * DIM + lane * 8))[t] = ev;  // out == quantized (straight-through)
    ((float4*)(quant + (size_t)row * DIM + lane * 8))[t] = ev;
  }
  #pragma unroll
  for (int off = 32; off > 0; off >>= 1) s += __shfl_down(s, off);
  if (lane == 0) wsum[wave] = s;
  __syncthreads();
  if (threadIdx.x == 0) {
    float tot = wsum[0] + wsum[1] + wsum[2] + wsum[3];
    atomicAdd(loss_slot, tot * (1.25f / (float)OUT_ELEMS));
  }
}

extern "C" void kernel_launch(void* const* d_in, const int* in_sizes, int n_in,
                              void* d_out, int out_size, void* d_ws, size_t ws_size,
                              hipStream_t stream) {
  const float* x   = (const float*)d_in[0];   // [16384, 512]
  const float* emb = (const float*)d_in[1];   // [8192, 512]
  float* out   = (float*)d_out;
  float* quant = out + OUT_ELEMS;
  float* loss  = out + 2 * OUT_ELEMS;

  char* ws = (char*)d_ws;
  f16*   x16    = (f16*)(ws);                           // 16.78 MB
  f16*   e16    = (f16*)(ws + 16777216);                //  8.39 MB
  float* enorm  = (float*)(ws + 25165824);              // 32 KB
  float* cd1    = (float*)(ws + 25198592);              // 4 MB
  int*   ci1    = (int*)  (ws + 29392896);              // 4 MB
  float* cd2    = (float*)(ws + 33587200);              // 4 MB
  int*   idx    = (int*)  (ws + 37781504);              // 64 KB
  int*   flag   = (int*)  (ws + 37847040);              // 64 KB
  int*   counter= (int*)  (ws + 37912576);              // 4 B (+pad)
  int*   flagged= (int*)  (ws + 37912832);              // 64 KB
  unsigned long long* packed = (unsigned long long*)(ws + 37978368); // 128 KB

  vq_split_kernel<<<OUT_ELEMS / (8 * 256), 256, 0, stream>>>(x, x16);
  vq_split_enorm_kernel<<<K_CODES * 64 / 256, 256, 0, stream>>>(emb, e16, enorm, counter);
  vq_argmin_mfma_kernel<<<dim3(N_ROWS / TM, K_CODES / TN), 256, 0, stream>>>(
      x16, e16, enorm, cd1, ci1, cd2);
  vq_merge2_kernel<<<N_ROWS / 256, 256, 0, stream>>>(
      cd1, ci1, cd2, idx, flag, counter, flagged, packed, loss);
  vq_rescan_kernel<<<2048, 256, 0, stream>>>(x, emb, enorm, counter, flagged, packed);
  vq_gather_kernel<<<N_ROWS / 4, 256, 0, stream>>>(x, emb, idx, flag, packed, out, quant, loss);
}

// Round 8
// 645.258 us; speedup vs baseline: 1.0307x; 1.0307x over previous
//
#include <hip/hip_runtime.h>

#define DIM 512
#define N_ROWS 16384
#define K_CODES 8192
#define BK 32
#define TM 128
#define TN 128
#define NG (K_CODES / TN)               // 64 code groups
#define OUT_ELEMS (N_ROWS * DIM)        // 8388608
#define MARGIN 0.125f                   // stage-1 (fp16 single-term) margin
#define MARGIN2 0.004f                  // stage-2 (fp16 3-term) margin
#define CAP 4096                        // max refined slots (nflag ~1400 expected)
#define RESCAN_CHUNK 1024
#define RESCAN_NCHUNK (K_CODES / RESCAN_CHUNK)  // 8
#define RESCAN_ROWS 8
#define NT (DIM / BK)                   // 16 K-steps

typedef _Float16 f16;
typedef _Float16 f16x8 __attribute__((ext_vector_type(8)));
typedef float f32x4 __attribute__((ext_vector_type(4)));

// monotone float->uint map: min on packed == (min dist, then min idx)
__device__ __forceinline__ unsigned long long pack_di(float d, int i) {
  unsigned u = __float_as_uint(d);
  u = (u & 0x80000000u) ? ~u : (u | 0x80000000u);
  return ((unsigned long long)u << 32) | (unsigned)i;
}

// ---------------- kernel 0: fp32 -> fp16 cast (x) ----------------
__global__ __launch_bounds__(256) void vq_split_kernel(const float* __restrict__ src,
                                                       f16* __restrict__ x16) {
  int i = (blockIdx.x * 256 + threadIdx.x) * 8;
  float4 v0 = *(const float4*)(src + i);
  float4 v1 = *(const float4*)(src + i + 4);
  float f[8] = {v0.x, v0.y, v0.z, v0.w, v1.x, v1.y, v1.z, v1.w};
  f16x8 h;
  #pragma unroll
  for (int j = 0; j < 8; ++j) h[j] = (f16)f[j];   // RNE, rel err <= 2^-11
  *(f16x8*)(x16 + i) = h;
}

// ---------------- kernel 1: emb fp16 hi/lo split + exact fp32 norms + counter zero ----------------
// one wave per code row: 64 lanes x 8 elems = 512.
// eh = fp16(e); el = fp16(e - eh)  (lo residual feeds the stage-2 3-term GEMM)
__global__ __launch_bounds__(256) void vq_split_enorm_kernel(
    const float* __restrict__ emb, f16* __restrict__ eh, f16* __restrict__ el,
    float* __restrict__ enorm, int* __restrict__ counter, int* __restrict__ rcounter) {
  int gid  = blockIdx.x * 256 + threadIdx.x;
  if (gid == 0) { *counter = 0; *rcounter = 0; }
  int code = gid >> 6;
  int lane = gid & 63;
  size_t off = (size_t)code * DIM + lane * 8;
  float4 v0 = *(const float4*)(emb + off);
  float4 v1 = *(const float4*)(emb + off + 4);
  float f[8] = {v0.x, v0.y, v0.z, v0.w, v1.x, v1.y, v1.z, v1.w};
  f16x8 h, l;
  float s = 0.0f;
  #pragma unroll
  for (int j = 0; j < 8; ++j) {
    f16 hj = (f16)f[j];
    h[j] = hj;
    l[j] = (f16)(f[j] - (float)hj);
    s = fmaf(f[j], f[j], s);
  }
  *(f16x8*)(eh + off) = h;
  *(f16x8*)(el + off) = l;
  #pragma unroll
  for (int o = 32; o > 0; o >>= 1) s += __shfl_down(s, o);
  if (lane == 0) enorm[code] = s;
}

// ---------------- async global->LDS 16B helper ----------------
__device__ __forceinline__ void gl2lds16(const f16* g, f16* l) {
  __builtin_amdgcn_global_load_lds((const __attribute__((address_space(1))) unsigned int*)g,
                                   (__attribute__((address_space(3))) unsigned int*)l,
                                   16, 0, 0);
}

__device__ __forceinline__ void top2_merge(float& d1, int& i1, float& d2,
                                           float od1, int oi1, float od2) {
  if (od1 < d1 || (od1 == d1 && oi1 < i1)) {
    d2 = fminf(d1, od2);
    d1 = od1; i1 = oi1;
  } else {
    d2 = fminf(d2, od1);
  }
}

// ---------------- kernel 2: stage-1 single-term fp16 MFMA GEMM + top-2 argmin ----------------
// EXACT round-3 kernel (233 us proven): BK=32 double-buffer with stage-ahead,
// one __syncthreads per K-step. Rows with top-2 gap < MARGIN go to stage-2.
// LDS tiles [128][BK=32] f16; XOR swizzle (conflict-free): chunk fq of row r
// at slot fq ^ ((r>>1)&3); gl2lds writes linearly so the swizzle is realized
// source-side: lane l fetches chunk (l&3)^((l>>3)&3) of row l>>2.
__global__ __launch_bounds__(256, 4) void vq_argmin_mfma_kernel(
    const f16* __restrict__ x16, const f16* __restrict__ e16,
    const float* __restrict__ enorm,
    float* __restrict__ cand_d1, int* __restrict__ cand_i1, float* __restrict__ cand_d2) {
  __shared__ __align__(16) f16 Ax[2][TM * BK];   // 8 KB per buffer
  __shared__ __align__(16) f16 Be[2][TN * BK];   // 8 KB per buffer
  __shared__ float red_d1[2][TM];
  __shared__ int   red_i1[2][TM];
  __shared__ float red_d2[2][TM];

  const int tid  = threadIdx.x;
  const int wave = tid >> 6;
  const int lane = tid & 63;
  const int bm = blockIdx.x, bn = blockIdx.y;
  const int wr = (wave >> 1) * 64;   // wave's row offset in tile (compute role)
  const int wc = (wave & 1) * 64;    // wave's col offset in tile

  const f16* gsrc0;
  int ldoff;
  {
    const int srow = lane >> 2;                              // 0..15
    const int scg  = ((lane & 3) ^ ((lane >> 3) & 3)) * 8;   // swizzled chunk * 8 elems
    const int rowoff = (wave & 1) * 64;
    if (wave < 2) { gsrc0 = x16 + (size_t)(bm * TM + rowoff + srow) * DIM + scg; }
    else          { gsrc0 = e16 + (size_t)(bn * TN + rowoff + srow) * DIM + scg; }
    ldoff = rowoff * BK;
  }
  f16* dstA0 = (wave < 2) ? &Ax[0][ldoff] : &Be[0][ldoff];
  f16* dstA1 = (wave < 2) ? &Ax[1][ldoff] : &Be[1][ldoff];

  f32x4 acc[4][4];
  #pragma unroll
  for (int i = 0; i < 4; ++i)
    #pragma unroll
    for (int j = 0; j < 4; ++j)
      acc[i][j] = (f32x4){0.f, 0.f, 0.f, 0.f};

  const int fr = lane & 15;
  const int fq = lane >> 4;
  const int sw8 = (fq ^ ((fr >> 1) & 3)) * 8;

  #pragma unroll
  for (int i = 0; i < 4; ++i)
    gl2lds16(gsrc0 + (size_t)(16 * i) * DIM, dstA0 + (16 * i) * BK);
  __syncthreads();

  #pragma unroll 2
  for (int s = 0; s < NT; ++s) {
    const int cur = s & 1;
    if (s + 1 < NT) {
      f16* nb = cur ? dstA0 : dstA1;
      const int k1 = (s + 1) * BK;
      #pragma unroll
      for (int i = 0; i < 4; ++i)
        gl2lds16(gsrc0 + (size_t)(16 * i) * DIM + k1, nb + (16 * i) * BK);
    }

    const f16* A = cur ? &Ax[1][0] : &Ax[0][0];
    const f16* B = cur ? &Be[1][0] : &Be[0][0];
    f16x8 a[4], b[4];
    #pragma unroll
    for (int f = 0; f < 4; ++f) {
      a[f] = *(const f16x8*)&A[(wr + f * 16 + fr) * BK + sw8];
      b[f] = *(const f16x8*)&B[(wc + f * 16 + fr) * BK + sw8];
    }
    #pragma unroll
    for (int mf = 0; mf < 4; ++mf)
      #pragma unroll
      for (int nf = 0; nf < 4; ++nf)
        acc[mf][nf] = __builtin_amdgcn_mfma_f32_16x16x32_f16(a[mf], b[nf], acc[mf][nf], 0, 0, 0);

    __syncthreads();
  }

  float en[4];
  #pragma unroll
  for (int nf = 0; nf < 4; ++nf)
    en[nf] = enorm[bn * TN + wc + nf * 16 + fr];

  #pragma unroll
  for (int mf = 0; mf < 4; ++mf) {
    #pragma unroll
    for (int reg = 0; reg < 4; ++reg) {
      float d1 = 3.4e38f, d2 = 3.4e38f;
      int i1 = 0;
      #pragma unroll
      for (int nf = 0; nf < 4; ++nf) {
        float d = en[nf] - 2.0f * acc[mf][nf][reg];
        int ci = bn * TN + wc + nf * 16 + fr;
        if (d < d1) { d2 = d1; d1 = d; i1 = ci; }
        else if (d < d2) { d2 = d; }
      }
      #pragma unroll
      for (int m = 1; m <= 8; m <<= 1) {
        float od1 = __shfl_xor(d1, m, 16);
        int   oi1 = __shfl_xor(i1, m, 16);
        float od2 = __shfl_xor(d2, m, 16);
        top2_merge(d1, i1, d2, od1, oi1, od2);
      }
      if (fr == 0) {
        int row = wr + mf * 16 + fq * 4 + reg;
        red_d1[wave & 1][row] = d1;
        red_i1[wave & 1][row] = i1;
        red_d2[wave & 1][row] = d2;
      }
    }
  }
  __syncthreads();
  if (tid < TM) {
    float d1 = red_d1[0][tid]; int i1 = red_i1[0][tid]; float d2 = red_d2[0][tid];
    top2_merge(d1, i1, d2, red_d1[1][tid], red_i1[1][tid], red_d2[1][tid]);
    size_t o = (size_t)bn * N_ROWS + (size_t)bm * TM + tid;
    cand_d1[o] = d1; cand_i1[o] = i1; cand_d2[o] = d2;
  }
}

// ---------------- kernel 3: stage-1 merge -> idx, flag(slot+1), compacted list ----------------
__global__ __launch_bounds__(256) void vq_merge2_kernel(
    const float* __restrict__ cd1, const int* __restrict__ ci1, const float* __restrict__ cd2,
    int* __restrict__ idx, int* __restrict__ flag,
    int* __restrict__ counter, int* __restrict__ flagged,
    float* __restrict__ loss_slot) {
  int r = blockIdx.x * 256 + threadIdx.x;
  if (r == 0) *loss_slot = 0.0f;
  float d1 = 3.4e38f, d2 = 3.4e38f;
  int i1 = 0;
  for (int g = 0; g < NG; ++g) {
    size_t o = (size_t)g * N_ROWS + r;
    top2_merge(d1, i1, d2, cd1[o], ci1[o], cd2[o]);
  }
  idx[r] = i1;
  if (d2 - d1 < MARGIN) {
    int slot = atomicAdd(counter, 1);
    flag[r] = slot + 1;
    flagged[slot] = r;
  } else {
    flag[r] = 0;
  }
}

// ---------------- kernel 3.5: compact flagged x rows into fp16 hi/lo split ----------------
// slot s < nflag: xch[s] = fp16(x[flagged[s]]); xcl[s] = fp16(x - xch). Pads zeroed.
__global__ __launch_bounds__(256) void vq_compact_kernel(
    const float* __restrict__ x, const int* __restrict__ counter,
    const int* __restrict__ flagged,
    f16* __restrict__ xch, f16* __restrict__ xcl) {
  const int slot = blockIdx.x * 4 + (threadIdx.x >> 6);
  const int lane = threadIdx.x & 63;
  int nf = counter[0]; if (nf > CAP) nf = CAP;
  size_t doff = (size_t)slot * DIM + lane * 8;
  f16x8 h, l;
  if (slot < nf) {
    const int r = flagged[slot];
    size_t soff = (size_t)r * DIM + lane * 8;
    float4 v0 = *(const float4*)(x + soff);
    float4 v1 = *(const float4*)(x + soff + 4);
    float f[8] = {v0.x, v0.y, v0.z, v0.w, v1.x, v1.y, v1.z, v1.w};
    #pragma unroll
    for (int j = 0; j < 8; ++j) {
      f16 hj = (f16)f[j];
      h[j] = hj;
      l[j] = (f16)(f[j] - (float)hj);
    }
  } else {
    #pragma unroll
    for (int j = 0; j < 8; ++j) { h[j] = (f16)0.f; l[j] = (f16)0.f; }
  }
  *(f16x8*)(xch + doff) = h;
  *(f16x8*)(xcl + doff) = l;
}

// ---------------- kernel 4: stage-2 refine — 3-term fp16 MFMA GEMM on flagged rows ----------------
// sim = xh.eh + xh.el + xl.eh  (error ~1e-4 << MARGIN2). Round-0-proven
// single-buffer 2-barrier structure, wave w stages matrix w (8 issues x 16 rows).
// Same source/read XOR swizzle as stage-1.
__global__ __launch_bounds__(256, 4) void vq_refine_kernel(
    const f16* __restrict__ xch, const f16* __restrict__ xcl,
    const f16* __restrict__ eh, const f16* __restrict__ el,
    const float* __restrict__ enorm, const int* __restrict__ counter,
    float* __restrict__ cd1b, int* __restrict__ ci1b, float* __restrict__ cd2b) {
  __shared__ __align__(16) f16 Axh[TM * BK];
  __shared__ __align__(16) f16 Axl[TM * BK];
  __shared__ __align__(16) f16 Beh[TN * BK];
  __shared__ __align__(16) f16 Bel[TN * BK];
  __shared__ float red_d1[2][TM];
  __shared__ int   red_i1[2][TM];
  __shared__ float red_d2[2][TM];

  const int tid  = threadIdx.x;
  const int wave = tid >> 6;
  const int lane = tid & 63;
  const int bm = blockIdx.x, bn = blockIdx.y;
  int nflag = counter[0]; if (nflag > CAP) nflag = CAP;
  if (bm * TM >= nflag) return;   // uniform whole-block exit, no barriers crossed

  const int wr = (wave >> 1) * 64;
  const int wc = (wave & 1) * 64;

  const f16* gsrc0;
  f16* ldst;
  {
    const int srow = lane >> 2;
    const int scol = ((lane & 3) ^ ((lane >> 3) & 3)) * 8;
    if (wave == 0)      { gsrc0 = xch + (size_t)(bm * TM + srow) * DIM + scol; ldst = Axh; }
    else if (wave == 1) { gsrc0 = xcl + (size_t)(bm * TM + srow) * DIM + scol; ldst = Axl; }
    else if (wave == 2) { gsrc0 = eh  + (size_t)(bn * TN + srow) * DIM + scol; ldst = Beh; }
    else                { gsrc0 = el  + (size_t)(bn * TN + srow) * DIM + scol; ldst = Bel; }
  }

  f32x4 acc[4][4];
  #pragma unroll
  for (int i = 0; i < 4; ++i)
    #pragma unroll
    for (int j = 0; j < 4; ++j)
      acc[i][j] = (f32x4){0.f, 0.f, 0.f, 0.f};

  const int fr = lane & 15;
  const int fq = lane >> 4;
  const int sw8 = (fq ^ ((fr >> 1) & 3)) * 8;

  for (int k0 = 0; k0 < DIM; k0 += BK) {
    __syncthreads();
    #pragma unroll
    for (int i = 0; i < 8; ++i)
      gl2lds16(gsrc0 + (size_t)(16 * i) * DIM + k0, ldst + (16 * i) * BK);
    __syncthreads();

    f16x8 ah[4], al[4], bh[4], bl[4];
    #pragma unroll
    for (int f = 0; f < 4; ++f) {
      ah[f] = *(const f16x8*)&Axh[(wr + f * 16 + fr) * BK + sw8];
      al[f] = *(const f16x8*)&Axl[(wr + f * 16 + fr) * BK + sw8];
      bh[f] = *(const f16x8*)&Beh[(wc + f * 16 + fr) * BK + sw8];
      bl[f] = *(const f16x8*)&Bel[(wc + f * 16 + fr) * BK + sw8];
    }
    #pragma unroll
    for (int mf = 0; mf < 4; ++mf)
      #pragma unroll
      for (int nf = 0; nf < 4; ++nf) {
        acc[mf][nf] = __builtin_amdgcn_mfma_f32_16x16x32_f16(ah[mf], bh[nf], acc[mf][nf], 0, 0, 0);
        acc[mf][nf] = __builtin_amdgcn_mfma_f32_16x16x32_f16(ah[mf], bl[nf], acc[mf][nf], 0, 0, 0);
        acc[mf][nf] = __builtin_amdgcn_mfma_f32_16x16x32_f16(al[mf], bh[nf], acc[mf][nf], 0, 0, 0);
      }
  }

  float en[4];
  #pragma unroll
  for (int nf = 0; nf < 4; ++nf)
    en[nf] = enorm[bn * TN + wc + nf * 16 + fr];

  #pragma unroll
  for (int mf = 0; mf < 4; ++mf) {
    #pragma unroll
    for (int reg = 0; reg < 4; ++reg) {
      float d1 = 3.4e38f, d2 = 3.4e38f;
      int i1 = 0;
      #pragma unroll
      for (int nf = 0; nf < 4; ++nf) {
        float d = en[nf] - 2.0f * acc[mf][nf][reg];
        int ci = bn * TN + wc + nf * 16 + fr;
        if (d < d1) { d2 = d1; d1 = d; i1 = ci; }
        else if (d < d2) { d2 = d; }
      }
      #pragma unroll
      for (int m = 1; m <= 8; m <<= 1) {
        float od1 = __shfl_xor(d1, m, 16);
        int   oi1 = __shfl_xor(i1, m, 16);
        float od2 = __shfl_xor(d2, m, 16);
        top2_merge(d1, i1, d2, od1, oi1, od2);
      }
      if (fr == 0) {
        int row = wr + mf * 16 + fq * 4 + reg;
        red_d1[wave & 1][row] = d1;
        red_i1[wave & 1][row] = i1;
        red_d2[wave & 1][row] = d2;
      }
    }
  }
  __syncthreads();
  if (tid < TM) {
    float d1 = red_d1[0][tid]; int i1 = red_i1[0][tid]; float d2 = red_d2[0][tid];
    top2_merge(d1, i1, d2, red_d1[1][tid], red_i1[1][tid], red_d2[1][tid]);
    size_t o = (size_t)bn * CAP + (size_t)bm * TM + tid;
    cd1b[o] = d1; ci1b[o] = i1; cd2b[o] = d2;
  }
}

// ---------------- kernel 5: stage-2 merge -> idxR, flagR + residual rescan list ----------------
__global__ __launch_bounds__(256) void vq_merge2b_kernel(
    const float* __restrict__ cd1b, const int* __restrict__ ci1b, const float* __restrict__ cd2b,
    const int* __restrict__ counter,
    int* __restrict__ idxR, int* __restrict__ flagR,
    int* __restrict__ rcounter, int* __restrict__ rlist,
    unsigned long long* __restrict__ packed) {
  int s = blockIdx.x * 256 + threadIdx.x;   // slot
  float d1 = 3.4e38f, d2 = 3.4e38f;
  int i1 = 0;
  for (int g = 0; g < NG; ++g) {
    size_t o = (size_t)g * CAP + s;
    top2_merge(d1, i1, d2, cd1b[o], ci1b[o], cd2b[o]);
  }
  idxR[s] = i1;
  int f2 = (d2 - d1 < MARGIN2) ? 1 : 0;
  flagR[s] = f2;
  int nf = counter[0]; if (nf > CAP) nf = CAP;
  if (s < nf && f2) {
    int rs = atomicAdd(rcounter, 1);
    rlist[rs] = s;
    packed[s] = 0xFFFFFFFFFFFFFFFFULL;
  }
}

// ---------------- kernel 6: exact fp32 rescan (residual slots only) ----------------
// Round-3-proven structure (RESCAN_ROWS=8), indexed via rlist->flagged.
// Per-code arithmetic identical to the verified round-0 rescan.
__global__ __launch_bounds__(256) void vq_rescan_kernel(
    const float* __restrict__ x, const float* __restrict__ emb,
    const float* __restrict__ enorm,
    const int* __restrict__ rcounter, const int* __restrict__ rlist,
    const int* __restrict__ flagged,
    unsigned long long* __restrict__ packed) {
  __shared__ float4 xs[RESCAN_ROWS][DIM / 4];          // 16 KB
  __shared__ unsigned long long wmin[4][RESCAN_ROWS];  // 256 B
  const int t  = threadIdx.x;
  const int wv = t >> 6, ln = t & 63;
  const int rcnt    = rcounter[0];
  const int ngroups = (rcnt + RESCAN_ROWS - 1) / RESCAN_ROWS;
  const int nitems  = ngroups * RESCAN_NCHUNK;
  for (int item = blockIdx.x; item < nitems; item += gridDim.x) {
    const int g  = item / RESCAN_NCHUNK;
    const int c0 = (item % RESCAN_NCHUNK) * RESCAN_CHUNK;
    __syncthreads();
    #pragma unroll
    for (int u = 0; u < 4; ++u) {
      int i4 = u * 256 + t;
      int j = i4 >> 7, kk = i4 & 127;
      int rj = g * RESCAN_ROWS + j;
      if (rj < rcnt) xs[j][kk] = ((const float4*)(x + (size_t)flagged[rlist[rj]] * DIM))[kk];
    }
    __syncthreads();
    unsigned long long best[RESCAN_ROWS];
    #pragma unroll
    for (int j = 0; j < RESCAN_ROWS; ++j) best[j] = ~0ULL;
    #pragma unroll
    for (int cc = 0; cc < RESCAN_CHUNK / 256; ++cc) {
      const int c = c0 + cc * 256 + t;
      const float4* e4 = (const float4*)(emb + (size_t)c * DIM);
      float s0[RESCAN_ROWS], s1[RESCAN_ROWS], s2[RESCAN_ROWS], s3[RESCAN_ROWS];
      #pragma unroll
      for (int j = 0; j < RESCAN_ROWS; ++j) { s0[j] = s1[j] = s2[j] = s3[j] = 0.f; }
      for (int k = 0; k < DIM / 4; ++k) {
        float4 ev = e4[k];
        #pragma unroll
        for (int j = 0; j < RESCAN_ROWS; ++j) {
          float4 xv = xs[j][k];
          s0[j] = fmaf(xv.x, ev.x, s0[j]);
          s1[j] = fmaf(xv.y, ev.y, s1[j]);
          s2[j] = fmaf(xv.z, ev.z, s2[j]);
          s3[j] = fmaf(xv.w, ev.w, s3[j]);
        }
      }
      const float en = enorm[c];
      #pragma unroll
      for (int j = 0; j < RESCAN_ROWS; ++j) {
        float d = en - 2.0f * ((s0[j] + s1[j]) + (s2[j] + s3[j]));
        unsigned long long p = pack_di(d, c);
        if (p < best[j]) best[j] = p;
      }
    }
    #pragma unroll
    for (int j = 0; j < RESCAN_ROWS; ++j) {
      #pragma unroll
      for (int off = 32; off > 0; off >>= 1) {
        unsigned long long o = __shfl_down(best[j], off);
        if (o < best[j]) best[j] = o;
      }
    }
    if (ln == 0) {
      #pragma unroll
      for (int j = 0; j < RESCAN_ROWS; ++j) wmin[wv][j] = best[j];
    }
    __syncthreads();
    if (t < RESCAN_ROWS) {
      int rj = g * RESCAN_ROWS + t;
      if (rj < rcnt) {
        unsigned long long m = wmin[0][t];
        if (wmin[1][t] < m) m = wmin[1][t];
        if (wmin[2][t] < m) m = wmin[2][t];
        if (wmin[3][t] < m) m = wmin[3][t];
        atomicMin(&packed[rlist[rj]], m);
      }
    }
  }
}

// ---------------- kernel 7: gather + outputs + loss ----------------
__global__ __launch_bounds__(256) void vq_gather_kernel(
    const float* __restrict__ x, const float* __restrict__ emb,
    const int* __restrict__ idx, const int* __restrict__ flag,
    const int* __restrict__ flagR, const int* __restrict__ idxR,
    const unsigned long long* __restrict__ packed,
    float* __restrict__ out, float* __restrict__ quant,
    float* __restrict__ loss_slot) {
  __shared__ float wsum[4];
  const int wave = threadIdx.x >> 6;
  const int lane = threadIdx.x & 63;
  const int row  = blockIdx.x * 4 + wave;
  const int f    = flag[row];
  int code;
  if (f == 0) {
    code = idx[row];
  } else {
    int slot = f - 1;
    if (slot >= CAP) code = idx[row];   // overflow fallback (nflag > CAP; not expected)
    else code = flagR[slot] ? (int)(packed[slot] & 0xFFFFFFFFu) : idxR[slot];
  }
  const float4* xp = (const float4*)(x   + (size_t)row  * DIM + lane * 8);
  const float4* ep = (const float4*)(emb + (size_t)code * DIM + lane * 8);
  float s = 0.0f;
  #pragma unroll
  for (int t = 0; t < 2; ++t) {
    float4 xv = xp[t];
    float4 ev = ep[t];
    float dx = ev.x - xv.x, dy = ev.y - xv.y, dz = ev.z - xv.z, dw = ev.w - xv.w;
    s += dx * dx + dy * dy + dz * dz + dw * dw;
    ((float4*)(out   + (size_t)row * DIM + lane * 8))[t] = ev;
    ((float4*)(quant + (size_t)row * DIM + lane * 8))[t] = ev;
  }
  #pragma unroll
  for (int off = 32; off > 0; off >>= 1) s += __shfl_down(s, off);
  if (lane == 0) wsum[wave] = s;
  __syncthreads();
  if (threadIdx.x == 0) {
    float tot = wsum[0] + wsum[1] + wsum[2] + wsum[3];
    atomicAdd(loss_slot, tot * (1.25f / (float)OUT_ELEMS));
  }
}

extern "C" void kernel_launch(void* const* d_in, const int* in_sizes, int n_in,
                              void* d_out, int out_size, void* d_ws, size_t ws_size,
                              hipStream_t stream) {
  const float* x   = (const float*)d_in[0];   // [16384, 512]
  const float* emb = (const float*)d_in[1];   // [8192, 512]
  float* out   = (float*)d_out;
  float* quant = out + OUT_ELEMS;
  float* loss  = out + 2 * OUT_ELEMS;

  char* ws = (char*)d_ws;
  f16*   x16    = (f16*)(ws);                            // 16,777,216
  f16*   e16    = (f16*)(ws + 16777216);                 //  8,388,608 (eh)
  f16*   ecl    = (f16*)(ws + 25165824);                 //  8,388,608 (el)
  float* enorm  = (float*)(ws + 33554432);               //     65,536 (32K + pad)
  float* cd1    = (float*)(ws + 33619968);               //  4,194,304
  int*   ci1    = (int*)  (ws + 37814272);               //  4,194,304
  float* cd2    = (float*)(ws + 42008576);               //  4,194,304
  int*   idx    = (int*)  (ws + 46202880);               //     65,536
  int*   flag   = (int*)  (ws + 46268416);               //     65,536
  int*   flagged= (int*)  (ws + 46333952);               //     65,536
  int*   counter= (int*)  (ws + 46399488);               //  4 B (+pad)
  int*   rcounter=(int*)  (ws + 46399616);               //  4 B (+pad)
  f16*   xch    = (f16*)(ws + 46399744);                 //  4,194,304 (CAP x 512)
  f16*   xcl    = (f16*)(ws + 50594048);                 //  4,194,304
  float* cd1b   = (float*)(ws + 54788352);               //  1,048,576 (64 x CAP)
  int*   ci1b   = (int*)  (ws + 55836928);               //  1,048,576
  float* cd2b   = (float*)(ws + 56885504);               //  1,048,576
  int*   idxR   = (int*)  (ws + 57934080);               //     16,384
  int*   flagR  = (int*)  (ws + 57950464);               //     16,384
  int*   rlist  = (int*)  (ws + 57966848);               //     16,384
  unsigned long long* packed = (unsigned long long*)(ws + 57983232); // 32,768

  vq_split_kernel<<<OUT_ELEMS / (8 * 256), 256, 0, stream>>>(x, x16);
  vq_split_enorm_kernel<<<K_CODES * 64 / 256, 256, 0, stream>>>(emb, e16, ecl, enorm, counter, rcounter);
  vq_argmin_mfma_kernel<<<dim3(N_ROWS / TM, K_CODES / TN), 256, 0, stream>>>(
      x16, e16, enorm, cd1, ci1, cd2);
  vq_merge2_kernel<<<N_ROWS / 256, 256, 0, stream>>>(
      cd1, ci1, cd2, idx, flag, counter, flagged, loss);
  vq_compact_kernel<<<CAP / 4, 256, 0, stream>>>(x, counter, flagged, xch, xcl);
  vq_refine_kernel<<<dim3(CAP / TM, K_CODES / TN), 256, 0, stream>>>(
      xch, xcl, e16, ecl, enorm, counter, cd1b, ci1b, cd2b);
  vq_merge2b_kernel<<<CAP / 256, 256, 0, stream>>>(
      cd1b, ci1b, cd2b, counter, idxR, flagR, rcounter, rlist, packed);
  vq_rescan_kernel<<<2048, 256, 0, stream>>>(x, emb, enorm, rcounter, rlist, flagged, packed);
  vq_gather_kernel<<<N_ROWS / 4, 256, 0, stream>>>(
      x, emb, idx, flag, flagR, idxR, packed, out, quant, loss);
}

// Round 10
// 513.018 us; speedup vs baseline: 1.2964x; 1.2578x over previous
//
#include <hip/hip_runtime.h>

#define DIM 512
#define N_ROWS 16384
#define K_CODES 8192
#define BK 32
#define TM 128
#define TN 128
#define NG (K_CODES / TN)               // 64 code groups
#define OUT_ELEMS (N_ROWS * DIM)        // 8388608
#define MARGIN 0.125f
#define RESCAN_CHUNK 256
#define RESCAN_NCHUNK (K_CODES / RESCAN_CHUNK)  // 32
#define RESCAN_ROWS 8
#define NT (DIM / BK)                   // 16 K-steps

typedef _Float16 f16;
typedef _Float16 f16x8 __attribute__((ext_vector_type(8)));
typedef float f32x4 __attribute__((ext_vector_type(4)));

// monotone float->uint map: min on packed == (min dist, then min idx)
__device__ __forceinline__ unsigned long long pack_di(float d, int i) {
  unsigned u = __float_as_uint(d);
  u = (u & 0x80000000u) ? ~u : (u | 0x80000000u);
  return ((unsigned long long)u << 32) | (unsigned)i;
}

// ---------------- kernel 0: fp32 -> fp16 cast (x) ----------------
__global__ __launch_bounds__(256) void vq_split_kernel(const float* __restrict__ src,
                                                       f16* __restrict__ x16) {
  int i = (blockIdx.x * 256 + threadIdx.x) * 8;
  float4 v0 = *(const float4*)(src + i);
  float4 v1 = *(const float4*)(src + i + 4);
  float f[8] = {v0.x, v0.y, v0.z, v0.w, v1.x, v1.y, v1.z, v1.w};
  f16x8 h;
  #pragma unroll
  for (int j = 0; j < 8; ++j) h[j] = (f16)f[j];   // RNE, rel err <= 2^-11
  *(f16x8*)(x16 + i) = h;
}

// ---------------- kernel 1: emb fp16 cast + exact fp32 norms + counter zero ----------------
// one wave per code row: 64 lanes x 8 elems = 512
__global__ __launch_bounds__(256) void vq_split_enorm_kernel(
    const float* __restrict__ emb, f16* __restrict__ e16,
    float* __restrict__ enorm, int* __restrict__ counter) {
  int gid  = blockIdx.x * 256 + threadIdx.x;
  if (gid == 0) *counter = 0;
  int code = gid >> 6;
  int lane = gid & 63;
  size_t off = (size_t)code * DIM + lane * 8;
  float4 v0 = *(const float4*)(emb + off);
  float4 v1 = *(const float4*)(emb + off + 4);
  float f[8] = {v0.x, v0.y, v0.z, v0.w, v1.x, v1.y, v1.z, v1.w};
  f16x8 h;
  float s = 0.0f;
  #pragma unroll
  for (int j = 0; j < 8; ++j) {
    h[j] = (f16)f[j];
    s = fmaf(f[j], f[j], s);
  }
  *(f16x8*)(e16 + off) = h;
  #pragma unroll
  for (int o = 32; o > 0; o >>= 1) s += __shfl_down(s, o);
  if (lane == 0) enorm[code] = s;
}

// ---------------- async global->LDS 16B helper ----------------
__device__ __forceinline__ void gl2lds16(const f16* g, f16* l) {
  __builtin_amdgcn_global_load_lds((const __attribute__((address_space(1))) unsigned int*)g,
                                   (__attribute__((address_space(3))) unsigned int*)l,
                                   16, 0, 0);
}

__device__ __forceinline__ void top2_merge(float& d1, int& i1, float& d2,
                                           float od1, int oi1, float od2) {
  if (od1 < d1 || (od1 == d1 && oi1 < i1)) {
    d2 = fminf(d1, od2);
    d1 = od1; i1 = oi1;
  } else {
    d2 = fminf(d2, od1);
  }
}

// ---------------- kernel 2: single-term fp16 MFMA GEMM + top-2 argmin ----------------
// sim = x16.e16 (fp16 in, exact fp32 accumulate); dist = ||e||^2 - 2 sim.
// Rows with top-2 gap < MARGIN get the exact fp32 rescan, so argmin is exact.
//
// PROVEN round-3/8 structure (231.7 us, passed twice): BK=32 double-buffer
// with stage-ahead, one __syncthreads per K-step. NOTE (round-9 post-mortem):
// the triple-buffer + raw s_barrier + counted-vmcnt variant FAILED correctness
// (absmax 0.99) — raw s_barrier is not an IR-level memory fence, so plain-C++
// ds_reads can be reordered across it by the compiler. __syncthreads (fence +
// barrier + fence) is what makes this structure sound. Counted-vmcnt is parked
// until it can be race-screened.
//
// LDS tiles [128][BK=32] f16; XOR swizzle (r0-proven, conflict-free): chunk fq
// of row r at slot fq ^ ((r>>1)&3); gl2lds writes linearly so the swizzle is
// realized source-side: lane l fetches chunk (l&3)^((l>>3)&3) of row l>>2.
__global__ __launch_bounds__(256, 4) void vq_argmin_mfma_kernel(
    const f16* __restrict__ x16, const f16* __restrict__ e16,
    const float* __restrict__ enorm,
    float* __restrict__ cand_d1, int* __restrict__ cand_i1, float* __restrict__ cand_d2) {
  __shared__ __align__(16) f16 Ax[2][TM * BK];   // 8 KB per buffer
  __shared__ __align__(16) f16 Be[2][TN * BK];   // 8 KB per buffer
  __shared__ float red_d1[2][TM];
  __shared__ int   red_i1[2][TM];
  __shared__ float red_d2[2][TM];

  const int tid  = threadIdx.x;
  const int wave = tid >> 6;
  const int lane = tid & 63;
  const int bm = blockIdx.x, bn = blockIdx.y;
  const int wr = (wave >> 1) * 64;   // wave's row offset in tile (compute role)
  const int wc = (wave & 1) * 64;    // wave's col offset in tile

  const f16* gsrc0;
  int ldoff;
  {
    const int srow = lane >> 2;                              // 0..15
    const int scg  = ((lane & 3) ^ ((lane >> 3) & 3)) * 8;   // swizzled chunk * 8 elems
    const int rowoff = (wave & 1) * 64;
    if (wave < 2) { gsrc0 = x16 + (size_t)(bm * TM + rowoff + srow) * DIM + scg; }
    else          { gsrc0 = e16 + (size_t)(bn * TN + rowoff + srow) * DIM + scg; }
    ldoff = rowoff * BK;
  }
  f16* dstA0 = (wave < 2) ? &Ax[0][ldoff] : &Be[0][ldoff];
  f16* dstA1 = (wave < 2) ? &Ax[1][ldoff] : &Be[1][ldoff];

  f32x4 acc[4][4];
  #pragma unroll
  for (int i = 0; i < 4; ++i)
    #pragma unroll
    for (int j = 0; j < 4; ++j)
      acc[i][j] = (f32x4){0.f, 0.f, 0.f, 0.f};

  const int fr = lane & 15;
  const int fq = lane >> 4;
  const int sw8 = (fq ^ ((fr >> 1) & 3)) * 8;

  // prologue: stage K-step 0 into buffer 0
  #pragma unroll
  for (int i = 0; i < 4; ++i)
    gl2lds16(gsrc0 + (size_t)(16 * i) * DIM, dstA0 + (16 * i) * BK);
  __syncthreads();   // vmcnt(0) drain: step-0 tiles resident

  #pragma unroll 2
  for (int s = 0; s < NT; ++s) {
    const int cur = s & 1;
    // stage-ahead: next K-step into the other buffer BEFORE compute.
    // Safe: buf^1's readers finished before the barrier ending step s-1.
    if (s + 1 < NT) {
      f16* nb = cur ? dstA0 : dstA1;
      const int k1 = (s + 1) * BK;
      #pragma unroll
      for (int i = 0; i < 4; ++i)
        gl2lds16(gsrc0 + (size_t)(16 * i) * DIM + k1, nb + (16 * i) * BK);
    }

    const f16* A = cur ? &Ax[1][0] : &Ax[0][0];
    const f16* B = cur ? &Be[1][0] : &Be[0][0];
    f16x8 a[4], b[4];
    #pragma unroll
    for (int f = 0; f < 4; ++f) {
      a[f] = *(const f16x8*)&A[(wr + f * 16 + fr) * BK + sw8];
      b[f] = *(const f16x8*)&B[(wc + f * 16 + fr) * BK + sw8];
    }
    #pragma unroll
    for (int mf = 0; mf < 4; ++mf)
      #pragma unroll
      for (int nf = 0; nf < 4; ++nf)
        acc[mf][nf] = __builtin_amdgcn_mfma_f32_16x16x32_f16(a[mf], b[nf], acc[mf][nf], 0, 0, 0);

    __syncthreads();   // drains stage-ahead loads (covered by compute) + joins waves
  }

  // ---- epilogue: distances + per-row top-2 over this block's 128 cols ----
  float en[4];
  #pragma unroll
  for (int nf = 0; nf < 4; ++nf)
    en[nf] = enorm[bn * TN + wc + nf * 16 + fr];

  #pragma unroll
  for (int mf = 0; mf < 4; ++mf) {
    #pragma unroll
    for (int reg = 0; reg < 4; ++reg) {
      float d1 = 3.4e38f, d2 = 3.4e38f;
      int i1 = 0;
      #pragma unroll
      for (int nf = 0; nf < 4; ++nf) {   // ascending col keeps lowest idx on ties
        float d = en[nf] - 2.0f * acc[mf][nf][reg];
        int ci = bn * TN + wc + nf * 16 + fr;
        if (d < d1) { d2 = d1; d1 = d; i1 = ci; }
        else if (d < d2) { d2 = d; }
      }
      // butterfly over the 16 lanes (same fq) holding this row's 64 cols
      #pragma unroll
      for (int m = 1; m <= 8; m <<= 1) {
        float od1 = __shfl_xor(d1, m, 16);
        int   oi1 = __shfl_xor(i1, m, 16);
        float od2 = __shfl_xor(d2, m, 16);
        top2_merge(d1, i1, d2, od1, oi1, od2);
      }
      if (fr == 0) {
        int row = wr + mf * 16 + fq * 4 + reg;
        red_d1[wave & 1][row] = d1;
        red_i1[wave & 1][row] = i1;
        red_d2[wave & 1][row] = d2;
      }
    }
  }
  __syncthreads();
  if (tid < TM) {
    float d1 = red_d1[0][tid]; int i1 = red_i1[0][tid]; float d2 = red_d2[0][tid];
    top2_merge(d1, i1, d2, red_d1[1][tid], red_i1[1][tid], red_d2[1][tid]);
    size_t o = (size_t)bn * N_ROWS + (size_t)bm * TM + tid;
    cand_d1[o] = d1; cand_i1[o] = i1; cand_d2[o] = d2;
  }
}

// ---------------- kernel 3: merge 64 groups -> idx, flag + compacted work list ----------------
__global__ __launch_bounds__(256) void vq_merge2_kernel(
    const float* __restrict__ cd1, const int* __restrict__ ci1, const float* __restrict__ cd2,
    int* __restrict__ idx, int* __restrict__ flag,
    int* __restrict__ counter, int* __restrict__ flagged,
    unsigned long long* __restrict__ packed,
    float* __restrict__ loss_slot) {
  int r = blockIdx.x * 256 + threadIdx.x;
  if (r == 0) *loss_slot = 0.0f;
  float d1 = 3.4e38f, d2 = 3.4e38f;
  int i1 = 0;
  for (int g = 0; g < NG; ++g) {   // ascending g = ascending col blocks
    size_t o = (size_t)g * N_ROWS + r;
    top2_merge(d1, i1, d2, cd1[o], ci1[o], cd2[o]);
  }
  idx[r] = i1;
  int f = (d2 - d1 < MARGIN) ? 1 : 0;
  flag[r] = f;
  if (f) {
    packed[r] = 0xFFFFFFFFFFFFFFFFULL;
    int slot = atomicAdd(counter, 1);
    flagged[slot] = r;
  }
}

// ---------------- kernel 4: exact fp32 rescan, 8 rows x 256-code chunks ----------------
// Per-code arithmetic (s0..s3 lanes, (s0+s1)+(s2+s3)) kept bit-identical to the
// verified round-0 rescan. CHUNK=256 (was 1024): R7 showed the rescan is
// ~1-item-per-block latency-bound, so 4x items at 1/4 serial work each cuts
// the critical path (one code per thread per item).
__global__ __launch_bounds__(256) void vq_rescan_kernel(
    const float* __restrict__ x, const float* __restrict__ emb,
    const float* __restrict__ enorm,
    const int* __restrict__ counter, const int* __restrict__ flagged,
    unsigned long long* __restrict__ packed) {
  __shared__ float4 xs[RESCAN_ROWS][DIM / 4];          // 16 KB
  __shared__ unsigned long long wmin[4][RESCAN_ROWS];  // 256 B
  const int t  = threadIdx.x;
  const int wv = t >> 6, ln = t & 63;
  const int nflag   = counter[0];
  const int ngroups = (nflag + RESCAN_ROWS - 1) / RESCAN_ROWS;
  const int nitems  = ngroups * RESCAN_NCHUNK;
  for (int item = blockIdx.x; item < nitems; item += gridDim.x) {
    const int g  = item / RESCAN_NCHUNK;
    const int c0 = (item % RESCAN_NCHUNK) * RESCAN_CHUNK;
    __syncthreads();   // protect xs from previous iteration's readers
    #pragma unroll
    for (int u = 0; u < 4; ++u) {
      int i4 = u * 256 + t;                 // 0..1023 float4 slots
      int j = i4 >> 7, kk = i4 & 127;
      int rj = g * RESCAN_ROWS + j;
      if (rj < nflag) xs[j][kk] = ((const float4*)(x + (size_t)flagged[rj] * DIM))[kk];
    }
    __syncthreads();
    unsigned long long best[RESCAN_ROWS];
    #pragma unroll
    for (int j = 0; j < RESCAN_ROWS; ++j) best[j] = ~0ULL;
    {
      const int c = c0 + t;                 // CHUNK==256 -> one code per thread
      const float4* e4 = (const float4*)(emb + (size_t)c * DIM);
      float s0[RESCAN_ROWS], s1[RESCAN_ROWS], s2[RESCAN_ROWS], s3[RESCAN_ROWS];
      #pragma unroll
      for (int j = 0; j < RESCAN_ROWS; ++j) { s0[j] = s1[j] = s2[j] = s3[j] = 0.f; }
      for (int k = 0; k < DIM / 4; ++k) {
        float4 ev = e4[k];
        #pragma unroll
        for (int j = 0; j < RESCAN_ROWS; ++j) {
          float4 xv = xs[j][k];              // broadcast read, conflict-free
          s0[j] = fmaf(xv.x, ev.x, s0[j]);
          s1[j] = fmaf(xv.y, ev.y, s1[j]);
          s2[j] = fmaf(xv.z, ev.z, s2[j]);
          s3[j] = fmaf(xv.w, ev.w, s3[j]);
        }
      }
      const float en = enorm[c];
      #pragma unroll
      for (int j = 0; j < RESCAN_ROWS; ++j) {
        float d = en - 2.0f * ((s0[j] + s1[j]) + (s2[j] + s3[j]));
        unsigned long long p = pack_di(d, c);
        if (p < best[j]) best[j] = p;
      }
    }
    // wave reduce (packed u64 min == lexicographic (dist, idx) min)
    #pragma unroll
    for (int j = 0; j < RESCAN_ROWS; ++j) {
      #pragma unroll
      for (int off = 32; off > 0; off >>= 1) {
        unsigned long long o = __shfl_down(best[j], off);
        if (o < best[j]) best[j] = o;
      }
    }
    if (ln == 0) {
      #pragma unroll
      for (int j = 0; j < RESCAN_ROWS; ++j) wmin[wv][j] = best[j];
    }
    __syncthreads();
    if (t < RESCAN_ROWS) {
      int rj = g * RESCAN_ROWS + t;
      if (rj < nflag) {
        unsigned long long m = wmin[0][t];
        if (wmin[1][t] < m) m = wmin[1][t];
        if (wmin[2][t] < m) m = wmin[2][t];
        if (wmin[3][t] < m) m = wmin[3][t];
        atomicMin(&packed[flagged[rj]], m);
      }
    }
  }
}

// ---------------- kernel 5: gather + outputs + loss ----------------
__global__ __launch_bounds__(256) void vq_gather_kernel(
    const float* __restrict__ x, const float* __restrict__ emb,
    const int* __restrict__ idx, const int* __restrict__ flag,
    const unsigned long long* __restrict__ packed,
    float* __restrict__ out, float* __restrict__ quant,
    float* __restrict__ loss_slot) {
  __shared__ float wsum[4];
  const int wave = threadIdx.x >> 6;
  const int lane = threadIdx.x & 63;
  const int row  = blockIdx.x * 4 + wave;
  const int code = flag[row] ? (int)(packed[row] & 0xFFFFFFFFu) : idx[row];
  const float4* xp = (const float4*)(x   + (size_t)row  * DIM + lane * 8);
  const float4* ep = (const float4*)(emb + (size_t)code * DIM + lane * 8);
  float s = 0.0f;
  #pragma unroll
  for (int t = 0; t < 2; ++t) {
    float4 xv = xp[t];
    float4 ev = ep[t];
    float dx = ev.x - xv.x, dy = ev.y - xv.y, dz = ev.z - xv.z, dw = ev.w - xv.w;
    s += dx * dx + dy * dy + dz * dz + dw * dw;
    ((float4*)(out   + (size_t)row * DIM + lane * 8))[t] = ev;  // out == quantized (straight-through)
    ((float4*)(quant + (size_t)row * DIM + lane * 8))[t] = ev;
  }
  #pragma unroll
  for (int off = 32; off > 0; off >>= 1) s += __shfl_down(s, off);
  if (lane == 0) wsum[wave] = s;
  __syncthreads();
  if (threadIdx.x == 0) {
    float tot = wsum[0] + wsum[1] + wsum[2] + wsum[3];
    atomicAdd(loss_slot, tot * (1.25f / (float)OUT_ELEMS));
  }
}

extern "C" void kernel_launch(void* const* d_in, const int* in_sizes, int n_in,
                              void* d_out, int out_size, void* d_ws, size_t ws_size,
                              hipStream_t stream) {
  const float* x   = (const float*)d_in[0];   // [16384, 512]
  const float* emb = (const float*)d_in[1];   // [8192, 512]
  float* out   = (float*)d_out;
  float* quant = out + OUT_ELEMS;
  float* loss  = out + 2 * OUT_ELEMS;

  char* ws = (char*)d_ws;
  f16*   x16    = (f16*)(ws);                           // 16.78 MB
  f16*   e16    = (f16*)(ws + 16777216);                //  8.39 MB
  float* enorm  = (float*)(ws + 25165824);              // 32 KB
  float* cd1    = (float*)(ws + 25198592);              // 4 MB
  int*   ci1    = (int*)  (ws + 29392896);              // 4 MB
  float* cd2    = (float*)(ws + 33587200);              // 4 MB
  int*   idx    = (int*)  (ws + 37781504);              // 64 KB
  int*   flag   = (int*)  (ws + 37847040);              // 64 KB
  int*   counter= (int*)  (ws + 37912576);              // 4 B (+pad)
  int*   flagged= (int*)  (ws + 37912832);              // 64 KB
  unsigned long long* packed = (unsigned long long*)(ws + 37978368); // 128 KB

  vq_split_kernel<<<OUT_ELEMS / (8 * 256), 256, 0, stream>>>(x, x16);
  vq_split_enorm_kernel<<<K_CODES * 64 / 256, 256, 0, stream>>>(emb, e16, enorm, counter);
  vq_argmin_mfma_kernel<<<dim3(N_ROWS / TM, K_CODES / TN), 256, 0, stream>>>(
      x16, e16, enorm, cd1, ci1, cd2);
  vq_merge2_kernel<<<N_ROWS / 256, 256, 0, stream>>>(
      cd1, ci1, cd2, idx, flag, counter, flagged, packed, loss);
  vq_rescan_kernel<<<2048, 256, 0, stream>>>(x, emb, enorm, counter, flagged, packed);
  vq_gather_kernel<<<N_ROWS / 4, 256, 0, stream>>>(x, emb, idx, flag, packed, out, quant, loss);
}

// Round 11
// 443.098 us; speedup vs baseline: 1.5009x; 1.1578x over previous
//
#include <hip/hip_runtime.h>

#define DIM 512
#define N_ROWS 16384
#define K_CODES 8192
#define BK 32
#define TM 128
#define TN 128
#define NG (K_CODES / TN)               // 64 code groups
#define OUT_ELEMS (N_ROWS * DIM)        // 8388608
#define MARGIN 0.125f
#define CAP_ITEMS 262144                // (row,group) rescan items; ~3100 expected
#define NT (DIM / BK)                   // 16 K-steps

typedef _Float16 f16;
typedef _Float16 f16x8 __attribute__((ext_vector_type(8)));
typedef float f32x4 __attribute__((ext_vector_type(4)));

// monotone float->uint map: min on packed == (min dist, then min idx)
__device__ __forceinline__ unsigned long long pack_di(float d, int i) {
  unsigned u = __float_as_uint(d);
  u = (u & 0x80000000u) ? ~u : (u | 0x80000000u);
  return ((unsigned long long)u << 32) | (unsigned)i;
}

// ---------------- kernel 0: fp32 -> fp16 cast (x) ----------------
__global__ __launch_bounds__(256) void vq_split_kernel(const float* __restrict__ src,
                                                       f16* __restrict__ x16) {
  int i = (blockIdx.x * 256 + threadIdx.x) * 8;
  float4 v0 = *(const float4*)(src + i);
  float4 v1 = *(const float4*)(src + i + 4);
  float f[8] = {v0.x, v0.y, v0.z, v0.w, v1.x, v1.y, v1.z, v1.w};
  f16x8 h;
  #pragma unroll
  for (int j = 0; j < 8; ++j) h[j] = (f16)f[j];   // RNE, rel err <= 2^-11
  *(f16x8*)(x16 + i) = h;
}

// ---------------- kernel 1: emb fp16 cast + exact fp32 norms + counter zero ----------------
// one wave per code row: 64 lanes x 8 elems = 512
__global__ __launch_bounds__(256) void vq_split_enorm_kernel(
    const float* __restrict__ emb, f16* __restrict__ e16,
    float* __restrict__ enorm, int* __restrict__ rcounter) {
  int gid  = blockIdx.x * 256 + threadIdx.x;
  if (gid == 0) *rcounter = 0;
  int code = gid >> 6;
  int lane = gid & 63;
  size_t off = (size_t)code * DIM + lane * 8;
  float4 v0 = *(const float4*)(emb + off);
  float4 v1 = *(const float4*)(emb + off + 4);
  float f[8] = {v0.x, v0.y, v0.z, v0.w, v1.x, v1.y, v1.z, v1.w};
  f16x8 h;
  float s = 0.0f;
  #pragma unroll
  for (int j = 0; j < 8; ++j) {
    h[j] = (f16)f[j];
    s = fmaf(f[j], f[j], s);
  }
  *(f16x8*)(e16 + off) = h;
  #pragma unroll
  for (int o = 32; o > 0; o >>= 1) s += __shfl_down(s, o);
  if (lane == 0) enorm[code] = s;
}

// ---------------- async global->LDS 16B helper ----------------
__device__ __forceinline__ void gl2lds16(const f16* g, f16* l) {
  __builtin_amdgcn_global_load_lds((const __attribute__((address_space(1))) unsigned int*)g,
                                   (__attribute__((address_space(3))) unsigned int*)l,
                                   16, 0, 0);
}

__device__ __forceinline__ void top2_merge(float& d1, int& i1, float& d2,
                                           float od1, int oi1, float od2) {
  if (od1 < d1 || (od1 == d1 && oi1 < i1)) {
    d2 = fminf(d1, od2);
    d1 = od1; i1 = oi1;
  } else {
    d2 = fminf(d2, od1);
  }
}

// ---------------- kernel 2: single-term fp16 MFMA GEMM + top-2 argmin ----------------
// sim = x16.e16 (fp16 in, exact fp32 accumulate); dist = ||e||^2 - 2 sim.
// Rows with top-2 gap < MARGIN get exact fp32 refinement, so argmin is exact.
//
// PROVEN round-3/8/10 structure (232-236 us, passed 3x): BK=32 double-buffer
// with stage-ahead, one __syncthreads per K-step. NOTE (round-9 post-mortem):
// the triple-buffer + raw s_barrier + counted-vmcnt variant FAILED correctness
// (absmax 0.99) — raw s_barrier is not an IR-level memory fence, so plain-C++
// ds_reads can be reordered across it by the compiler. __syncthreads (fence +
// barrier + fence) is what makes this structure sound. Counted-vmcnt is parked.
//
// LDS tiles [128][BK=32] f16; XOR swizzle (r0-proven, conflict-free): chunk fq
// of row r at slot fq ^ ((r>>1)&3); gl2lds writes linearly so the swizzle is
// realized source-side: lane l fetches chunk (l&3)^((l>>3)&3) of row l>>2.
__global__ __launch_bounds__(256, 4) void vq_argmin_mfma_kernel(
    const f16* __restrict__ x16, const f16* __restrict__ e16,
    const float* __restrict__ enorm,
    float* __restrict__ cand_d1, int* __restrict__ cand_i1, float* __restrict__ cand_d2) {
  __shared__ __align__(16) f16 Ax[2][TM * BK];   // 8 KB per buffer
  __shared__ __align__(16) f16 Be[2][TN * BK];   // 8 KB per buffer
  __shared__ float red_d1[2][TM];
  __shared__ int   red_i1[2][TM];
  __shared__ float red_d2[2][TM];

  const int tid  = threadIdx.x;
  const int wave = tid >> 6;
  const int lane = tid & 63;
  const int bm = blockIdx.x, bn = blockIdx.y;
  const int wr = (wave >> 1) * 64;   // wave's row offset in tile (compute role)
  const int wc = (wave & 1) * 64;    // wave's col offset in tile

  const f16* gsrc0;
  int ldoff;
  {
    const int srow = lane >> 2;                              // 0..15
    const int scg  = ((lane & 3) ^ ((lane >> 3) & 3)) * 8;   // swizzled chunk * 8 elems
    const int rowoff = (wave & 1) * 64;
    if (wave < 2) { gsrc0 = x16 + (size_t)(bm * TM + rowoff + srow) * DIM + scg; }
    else          { gsrc0 = e16 + (size_t)(bn * TN + rowoff + srow) * DIM + scg; }
    ldoff = rowoff * BK;
  }
  f16* dstA0 = (wave < 2) ? &Ax[0][ldoff] : &Be[0][ldoff];
  f16* dstA1 = (wave < 2) ? &Ax[1][ldoff] : &Be[1][ldoff];

  f32x4 acc[4][4];
  #pragma unroll
  for (int i = 0; i < 4; ++i)
    #pragma unroll
    for (int j = 0; j < 4; ++j)
      acc[i][j] = (f32x4){0.f, 0.f, 0.f, 0.f};

  const int fr = lane & 15;
  const int fq = lane >> 4;
  const int sw8 = (fq ^ ((fr >> 1) & 3)) * 8;

  // prologue: stage K-step 0 into buffer 0
  #pragma unroll
  for (int i = 0; i < 4; ++i)
    gl2lds16(gsrc0 + (size_t)(16 * i) * DIM, dstA0 + (16 * i) * BK);
  __syncthreads();   // vmcnt(0) drain: step-0 tiles resident

  #pragma unroll 2
  for (int s = 0; s < NT; ++s) {
    const int cur = s & 1;
    // stage-ahead: next K-step into the other buffer BEFORE compute.
    // Safe: buf^1's readers finished before the barrier ending step s-1.
    if (s + 1 < NT) {
      f16* nb = cur ? dstA0 : dstA1;
      const int k1 = (s + 1) * BK;
      #pragma unroll
      for (int i = 0; i < 4; ++i)
        gl2lds16(gsrc0 + (size_t)(16 * i) * DIM + k1, nb + (16 * i) * BK);
    }

    const f16* A = cur ? &Ax[1][0] : &Ax[0][0];
    const f16* B = cur ? &Be[1][0] : &Be[0][0];
    f16x8 a[4], b[4];
    #pragma unroll
    for (int f = 0; f < 4; ++f) {
      a[f] = *(const f16x8*)&A[(wr + f * 16 + fr) * BK + sw8];
      b[f] = *(const f16x8*)&B[(wc + f * 16 + fr) * BK + sw8];
    }
    #pragma unroll
    for (int mf = 0; mf < 4; ++mf)
      #pragma unroll
      for (int nf = 0; nf < 4; ++nf)
        acc[mf][nf] = __builtin_amdgcn_mfma_f32_16x16x32_f16(a[mf], b[nf], acc[mf][nf], 0, 0, 0);

    __syncthreads();   // drains stage-ahead loads (covered by compute) + joins waves
  }

  // ---- epilogue: distances + per-row top-2 over this block's 128 cols ----
  float en[4];
  #pragma unroll
  for (int nf = 0; nf < 4; ++nf)
    en[nf] = enorm[bn * TN + wc + nf * 16 + fr];

  #pragma unroll
  for (int mf = 0; mf < 4; ++mf) {
    #pragma unroll
    for (int reg = 0; reg < 4; ++reg) {
      float d1 = 3.4e38f, d2 = 3.4e38f;
      int i1 = 0;
      #pragma unroll
      for (int nf = 0; nf < 4; ++nf) {   // ascending col keeps lowest idx on ties
        float d = en[nf] - 2.0f * acc[mf][nf][reg];
        int ci = bn * TN + wc + nf * 16 + fr;
        if (d < d1) { d2 = d1; d1 = d; i1 = ci; }
        else if (d < d2) { d2 = d; }
      }
      // butterfly over the 16 lanes (same fq) holding this row's 64 cols
      #pragma unroll
      for (int m = 1; m <= 8; m <<= 1) {
        float od1 = __shfl_xor(d1, m, 16);
        int   oi1 = __shfl_xor(i1, m, 16);
        float od2 = __shfl_xor(d2, m, 16);
        top2_merge(d1, i1, d2, od1, oi1, od2);
      }
      if (fr == 0) {
        int row = wr + mf * 16 + fq * 4 + reg;
        red_d1[wave & 1][row] = d1;
        red_i1[wave & 1][row] = i1;
        red_d2[wave & 1][row] = d2;
      }
    }
  }
  __syncthreads();
  if (tid < TM) {
    float d1 = red_d1[0][tid]; int i1 = red_i1[0][tid]; float d2 = red_d2[0][tid];
    top2_merge(d1, i1, d2, red_d1[1][tid], red_i1[1][tid], red_d2[1][tid]);
    size_t o = (size_t)bn * N_ROWS + (size_t)bm * TM + tid;
    cand_d1[o] = d1; cand_i1[o] = i1; cand_d2[o] = d2;
  }
}

// ---------------- kernel 3: merge 64 groups -> idx, flag + pruned rescan items ----------------
// For flagged rows (gap < MARGIN), emit (row, group) items only for groups
// whose stage-1 top-1 distance cd1_g <= d1 + MARGIN. Sufficiency: with
// per-distance error <= E = MARGIN/2 (the same bound the unflagged path
// relies on), the true argmin c* has comp(c*) <= d1 + 2E = d1 + MARGIN, so
// its group's cd1_g <= comp(c*) <= d1 + MARGIN and the group is scanned.
// The winner's own group always qualifies (cd1 = d1).
__global__ __launch_bounds__(256) void vq_merge2_kernel(
    const float* __restrict__ cd1, const int* __restrict__ ci1, const float* __restrict__ cd2,
    int* __restrict__ idx, int* __restrict__ flag,
    int* __restrict__ rcounter, int* __restrict__ item_row, int* __restrict__ item_grp,
    unsigned long long* __restrict__ packed,
    float* __restrict__ loss_slot) {
  int r = blockIdx.x * 256 + threadIdx.x;
  if (r == 0) *loss_slot = 0.0f;
  float d1 = 3.4e38f, d2 = 3.4e38f;
  int i1 = 0;
  for (int g = 0; g < NG; ++g) {   // ascending g = ascending col blocks
    size_t o = (size_t)g * N_ROWS + r;
    top2_merge(d1, i1, d2, cd1[o], ci1[o], cd2[o]);
  }
  idx[r] = i1;
  int f = (d2 - d1 < MARGIN) ? 1 : 0;
  flag[r] = f;
  if (f) {
    packed[r] = 0xFFFFFFFFFFFFFFFFULL;
    const float thresh = d1 + MARGIN;
    for (int g = 0; g < NG; ++g) {
      if (cd1[(size_t)g * N_ROWS + r] <= thresh) {
        int slot = atomicAdd(rcounter, 1);
        if (slot < CAP_ITEMS) { item_row[slot] = r; item_grp[slot] = g; }
      }
    }
  }
}

// ---------------- kernel 4: exact fp32 rescan of pruned (row, group) items ----------------
// One 128-thread block per item iteration: stage x row (2KB) in LDS, thread t
// computes the exact fp32 distance of code g*128+t (per-code arithmetic
// bit-identical to the verified round-0 rescan), wave-reduce packed u64 min,
// one atomicMin per item.
__global__ __launch_bounds__(128) void vq_rescan_kernel(
    const float* __restrict__ x, const float* __restrict__ emb,
    const float* __restrict__ enorm,
    const int* __restrict__ rcounter,
    const int* __restrict__ item_row, const int* __restrict__ item_grp,
    unsigned long long* __restrict__ packed) {
  __shared__ float4 xs[DIM / 4];            // 2 KB
  __shared__ unsigned long long wred[2];
  const int t = threadIdx.x;
  int nitems = rcounter[0];
  if (nitems > CAP_ITEMS) nitems = CAP_ITEMS;
  for (int item = blockIdx.x; item < nitems; item += gridDim.x) {
    const int r = item_row[item];
    const int g = item_grp[item];
    __syncthreads();   // protect xs from previous iteration's readers
    xs[t] = ((const float4*)(x + (size_t)r * DIM))[t];   // 128 x float4 = 512
    __syncthreads();
    const int c = g * 128 + t;
    const float4* e4 = (const float4*)(emb + (size_t)c * DIM);
    float s0 = 0.f, s1 = 0.f, s2 = 0.f, s3 = 0.f;
    for (int k = 0; k < DIM / 4; ++k) {
      float4 xv = xs[k]; float4 ev = e4[k];
      s0 = fmaf(xv.x, ev.x, s0); s1 = fmaf(xv.y, ev.y, s1);
      s2 = fmaf(xv.z, ev.z, s2); s3 = fmaf(xv.w, ev.w, s3);
    }
    float d = enorm[c] - 2.0f * ((s0 + s1) + (s2 + s3));
    unsigned long long p = pack_di(d, c);
    #pragma unroll
    for (int off = 32; off > 0; off >>= 1) {
      unsigned long long o = __shfl_down(p, off);
      if (o < p) p = o;
    }
    if ((t & 63) == 0) wred[t >> 6] = p;
    __syncthreads();
    if (t == 0) {
      unsigned long long m = wred[0];
      if (wred[1] < m) m = wred[1];
      atomicMin(&packed[r], m);
    }
  }
}

// ---------------- kernel 5: gather + outputs + loss ----------------
__global__ __launch_bounds__(256) void vq_gather_kernel(
    const float* __restrict__ x, const float* __restrict__ emb,
    const int* __restrict__ idx, const int* __restrict__ flag,
    const unsigned long long* __restrict__ packed,
    float* __restrict__ out, float* __restrict__ quant,
    float* __restrict__ loss_slot) {
  __shared__ float wsum[4];
  const int wave = threadIdx.x >> 6;
  const int lane = threadIdx.x & 63;
  const int row  = blockIdx.x * 4 + wave;
  const int code = flag[row] ? (int)(packed[row] & 0xFFFFFFFFu) : idx[row];
  const float4* xp = (const float4*)(x   + (size_t)row  * DIM + lane * 8);
  const float4* ep = (const float4*)(emb + (size_t)code * DIM + lane * 8);
  float s = 0.0f;
  #pragma unroll
  for (int t = 0; t < 2; ++t) {
    float4 xv = xp[t];
    float4 ev = ep[t];
    float dx = ev.x - xv.x, dy = ev.y - xv.y, dz = ev.z - xv.z, dw = ev.w - xv.w;
    s += dx * dx + dy * dy + dz * dz + dw * dw;
    ((float4*)(out   + (size_t)row * DIM + lane * 8))[t] = ev;  // out == quantized (straight-through)
    ((float4*)(quant + (size_t)row * DIM + lane * 8))[t] = ev;
  }
  #pragma unroll
  for (int off = 32; off > 0; off >>= 1) s += __shfl_down(s, off);
  if (lane == 0) wsum[wave] = s;
  __syncthreads();
  if (threadIdx.x == 0) {
    float tot = wsum[0] + wsum[1] + wsum[2] + wsum[3];
    atomicAdd(loss_slot, tot * (1.25f / (float)OUT_ELEMS));
  }
}

extern "C" void kernel_launch(void* const* d_in, const int* in_sizes, int n_in,
                              void* d_out, int out_size, void* d_ws, size_t ws_size,
                              hipStream_t stream) {
  const float* x   = (const float*)d_in[0];   // [16384, 512]
  const float* emb = (const float*)d_in[1];   // [8192, 512]
  float* out   = (float*)d_out;
  float* quant = out + OUT_ELEMS;
  float* loss  = out + 2 * OUT_ELEMS;

  char* ws = (char*)d_ws;
  f16*   x16    = (f16*)(ws);                           // 16.78 MB
  f16*   e16    = (f16*)(ws + 16777216);                //  8.39 MB
  float* enorm  = (float*)(ws + 25165824);              // 32 KB
  float* cd1    = (float*)(ws + 25198592);              // 4 MB
  int*   ci1    = (int*)  (ws + 29392896);              // 4 MB
  float* cd2    = (float*)(ws + 33587200);              // 4 MB
  int*   idx    = (int*)  (ws + 37781504);              // 64 KB
  int*   flag   = (int*)  (ws + 37847040);              // 64 KB
  int*   rcounter=(int*)  (ws + 37912576);              // 4 B (+pad)
  unsigned long long* packed = (unsigned long long*)(ws + 37912832); // 128 KB
  int*   item_row=(int*)  (ws + 38043904);              // 1 MB (262144 x 4)
  int*   item_grp=(int*)  (ws + 39092480);              // 1 MB

  vq_split_kernel<<<OUT_ELEMS / (8 * 256), 256, 0, stream>>>(x, x16);
  vq_split_enorm_kernel<<<K_CODES * 64 / 256, 256, 0, stream>>>(emb, e16, enorm, rcounter);
  vq_argmin_mfma_kernel<<<dim3(N_ROWS / TM, K_CODES / TN), 256, 0, stream>>>(
      x16, e16, enorm, cd1, ci1, cd2);
  vq_merge2_kernel<<<N_ROWS / 256, 256, 0, stream>>>(
      cd1, ci1, cd2, idx, flag, rcounter, item_row, item_grp, packed, loss);
  vq_rescan_kernel<<<2048, 128, 0, stream>>>(
      x, emb, enorm, rcounter, item_row, item_grp, packed);
  vq_gather_kernel<<<N_ROWS / 4, 256, 0, stream>>>(x, emb, idx, flag, packed, out, quant, loss);
}